// Round 3
// baseline (47257.562 us; speedup 1.0000x reference)
//
#include <hip/hip_runtime.h>
#include <stdint.h>

typedef unsigned short u16;
typedef __attribute__((ext_vector_type(8))) short short8;
typedef __attribute__((ext_vector_type(4))) float f32x4;

#define BB 256
#define SS 128
#define TT 128
#define EE 512
#define HH 1024
#define VV 256

#define BK 64
#define LDSP 72   // padded LDS row length in bf16 elems (144 B = 9*16, keeps 16B alignment)
#define CH 8      // encoder pre-GEMM chunk (timesteps)

__device__ __forceinline__ float bf2f(u16 u){
    union { unsigned int i; float f; } v; v.i = ((unsigned int)u) << 16; return v.f;
}
__device__ __forceinline__ u16 f2bf(float f){
    union { float f; unsigned int i; } v; v.f = f;
    return (u16)((v.i + 0x7fffu + ((v.i >> 16) & 1u)) >> 16);
}
__device__ __forceinline__ float rcp_(float x){ return __builtin_amdgcn_rcpf(x); }
__device__ __forceinline__ float sigm_(float x){ return rcp_(1.f + __expf(-x)); }
__device__ __forceinline__ float tanh_(float x){ return 1.f - 2.f*rcp_(__expf(2.f*x) + 1.f); }

struct GArgs {
    const u16* A;  const u16* A2; long lda;     // A (M,K) bf16 hi / lo
    const u16* Bw; const u16* B2; long K;       // B (N,K) bf16 hi / lo, ldb == K
    const float* bias;                          // len N (indexed by col), nullable
    u16* Cb; float* Cf; long ldc;               // stores
    const u16* pre; long ldpre;                 // LSTM: add pre[row,col], nullable
    float* cst; long hid;                       // LSTM: c state (M, hid) f32
    u16* h1; u16* h1l; long ldh1;               // LSTM: h dest (+lo if split)
    u16* h2; u16* h2l; long ldh2;               // LSTM: optional 2nd h dest
};

// MODE: 0 = store bf16, 1 = store f32, 2 = fused LSTM cell (gate-interleaved cols)
template<int BMW, int BNW, int MODE, int SPLIT>
__device__ __forceinline__ void gemm_core(const GArgs& g)
{
    constexpr int BM = BMW*64, BN = BNW*64;
    constexpr int NT = BMW*BNW*64;
    constexpr int AE = BM*LDSP, BE = BN*LDSP;
    static_assert((BM*8) % NT == 0 && (BN*8) % NT == 0, "staging");
    __shared__ __align__(16) u16 sA[(SPLIT+1)*AE];
    __shared__ __align__(16) u16 sB[(SPLIT+1)*BE];
    const int tid = threadIdx.x;
    const int lane = tid & 63, wave = tid >> 6;
    const int wn = wave % BNW, wm = wave / BNW;
    const int l15 = lane & 15, quad = lane >> 4;
    const long m0 = (long)blockIdx.y * BM, n0 = (long)blockIdx.x * BN;

    f32x4 acc[4][4];
    #pragma unroll
    for (int a=0;a<4;a++)
    #pragma unroll
    for (int c=0;c<4;c++){ f32x4 z = {0.f,0.f,0.f,0.f}; acc[a][c] = z; }

    for (long k0 = 0; k0 < g.K; k0 += BK){
        #pragma unroll
        for (int i = 0; i < BM*8/NT; i++){
            int c = tid + i*NT;
            int r = c >> 3, c8 = (c & 7) * 8;
            *(int4*)&sA[r*LDSP + c8] = *(const int4*)(g.A + (m0 + r)*g.lda + k0 + c8);
            if (SPLIT)
                *(int4*)&sA[AE + r*LDSP + c8] = *(const int4*)(g.A2 + (m0 + r)*g.lda + k0 + c8);
        }
        #pragma unroll
        for (int i = 0; i < BN*8/NT; i++){
            int c = tid + i*NT;
            int r = c >> 3, c8 = (c & 7) * 8;
            *(int4*)&sB[r*LDSP + c8] = *(const int4*)(g.Bw + (n0 + r)*g.K + k0 + c8);
            if (SPLIT)
                *(int4*)&sB[BE + r*LDSP + c8] = *(const int4*)(g.B2 + (n0 + r)*g.K + k0 + c8);
        }
        __syncthreads();
        #pragma unroll
        for (int ks = 0; ks < 2; ks++){
            const int ko = ks*32 + quad*8;
            short8 ah[4], bh[4], al[4], bl[4];
            #pragma unroll
            for (int mi=0; mi<4; mi++){
                int ra = (wm*64 + mi*16 + l15)*LDSP + ko;
                ah[mi] = *(const short8*)&sA[ra];
                if (SPLIT) al[mi] = *(const short8*)&sA[AE + ra];
            }
            #pragma unroll
            for (int ni=0; ni<4; ni++){
                int rb = (wn*64 + ni*16 + l15)*LDSP + ko;
                bh[ni] = *(const short8*)&sB[rb];
                if (SPLIT) bl[ni] = *(const short8*)&sB[BE + rb];
            }
            #pragma unroll
            for (int mi=0; mi<4; mi++)
            #pragma unroll
            for (int ni=0; ni<4; ni++){
                acc[mi][ni] = __builtin_amdgcn_mfma_f32_16x16x32_bf16(ah[mi], bh[ni], acc[mi][ni], 0,0,0);
                if (SPLIT){
                    acc[mi][ni] = __builtin_amdgcn_mfma_f32_16x16x32_bf16(al[mi], bh[ni], acc[mi][ni], 0,0,0);
                    acc[mi][ni] = __builtin_amdgcn_mfma_f32_16x16x32_bf16(ah[mi], bl[ni], acc[mi][ni], 0,0,0);
                }
            }
        }
        __syncthreads();
    }

    // epilogue: C/D layout col = lane&15, row = quad*4 + reg  [m89-verified]
    #pragma unroll
    for (int mi=0; mi<4; mi++)
    #pragma unroll
    for (int ni=0; ni<4; ni++)
    #pragma unroll
    for (int r=0; r<4; r++){
        long row = m0 + wm*64 + mi*16 + quad*4 + r;
        long col = n0 + wn*64 + ni*16 + l15;
        float v = acc[mi][ni][r];
        if (g.bias) v += g.bias[col];
        if (MODE == 2){
            if (g.pre) v += bf2f(g.pre[row*g.ldpre + col]);
            // gates interleaved: col = j*4 + q, q in {i,f,g,o}; 4 gates in 4 adjacent lanes
            float gf = __shfl_xor(v, 1);
            float gg = __shfl_xor(v, 2);
            float go = __shfl_xor(v, 3);
            if ((lane & 3) == 0){
                long j = col >> 2;
                float co = g.cst[row*g.hid + j];
                float cn = sigm_(gf)*co + sigm_(v)*tanh_(gg);
                g.cst[row*g.hid + j] = cn;
                float hn = sigm_(go)*tanh_(cn);
                u16 hb = f2bf(hn);
                u16 lb = 0;
                if (SPLIT) lb = f2bf(hn - bf2f(hb));
                g.h1[row*g.ldh1 + j] = hb;
                if (SPLIT) g.h1l[row*g.ldh1 + j] = lb;
                if (g.h2){
                    g.h2[row*g.ldh2 + j] = hb;
                    if (SPLIT) g.h2l[row*g.ldh2 + j] = lb;
                }
            }
        } else if (MODE == 1){
            g.Cf[row*g.ldc + col] = v;
        } else {
            g.Cb[row*g.ldc + col] = f2bf(v);
        }
    }
}

template<int BMW,int BNW,int MODE,int SPLIT>
__global__ __launch_bounds__(BMW*BNW*64)
void gemm_kernel(GArgs g){ gemm_core<BMW,BNW,MODE,SPLIT>(g); }

// twin launch for fwd+bwd encoder directions (blockIdx.z selects)
template<int BMW,int BNW>
__global__ __launch_bounds__(BMW*BNW*64)
void lstm_step2_kernel(GArgs gf, GArgs gb){
    if (blockIdx.z == 0) gemm_core<BMW,BNW,2,0>(gf);
    else                 gemm_core<BMW,BNW,2,0>(gb);
}

// ---------------- attention (per decoder step) ----------------
__global__ __launch_bounds__(256)
void attn_kernel(const u16* __restrict__ enc_proj, const u16* __restrict__ enc_out,
                 const float* __restrict__ qp, const float* __restrict__ w2,
                 const float* __restrict__ b2p,
                 const int* __restrict__ src, const int* __restrict__ tgt,
                 const float* __restrict__ dec_embed,
                 float* __restrict__ out1,
                 u16* __restrict__ a0h, u16* __restrict__ a0l, int n)
{
    int b = blockIdx.x;
    int tid = threadIdx.x;
    int lane = tid & 63, wave = tid >> 6;
    __shared__ float sE[SS];
    __shared__ float sAs[SS];
    float qr[16], wr[16];
    const float* qb = qp + (size_t)b*HH;
    #pragma unroll
    for (int j=0;j<8;j++){
        qr[j]   = qb[lane*8 + j];        wr[j]   = w2[lane*8 + j];
        qr[8+j] = qb[512 + lane*8 + j];  wr[8+j] = w2[512 + lane*8 + j];
    }
    float b2 = b2p[0];
    for (int ii=0; ii<32; ii++){
        int s = wave*32 + ii;
        const u16* row = enc_proj + ((size_t)b*SS + s)*HH;
        int4 r0 = *(const int4*)(row + lane*8);
        int4 r1 = *(const int4*)(row + 512 + lane*8);
        const u16* u0 = (const u16*)&r0;
        const u16* u1 = (const u16*)&r1;
        float acc = 0.f;
        #pragma unroll
        for (int j=0;j<8;j++) acc += tanh_(bf2f(u0[j]) + qr[j]) * wr[j];
        #pragma unroll
        for (int j=0;j<8;j++) acc += tanh_(bf2f(u1[j]) + qr[8+j]) * wr[8+j];
        #pragma unroll
        for (int off=32; off; off>>=1) acc += __shfl_xor(acc, off);
        if (lane == 0){
            float e = acc + b2;
            if (src[b*SS + s] == 0) e = -1e30f;
            sE[s] = e;
        }
    }
    __syncthreads();
    if (wave == 0){
        float v0 = sE[lane], v1 = sE[64 + lane];
        float m = fmaxf(v0, v1);
        #pragma unroll
        for (int off=32; off; off>>=1) m = fmaxf(m, __shfl_xor(m, off));
        float p0 = __expf(v0 - m), p1 = __expf(v1 - m);
        float sum = p0 + p1;
        #pragma unroll
        for (int off=32; off; off>>=1) sum += __shfl_xor(sum, off);
        float inv = 1.f / sum;
        float a0 = p0 * inv, a1 = p1 * inv;
        sAs[lane] = a0; sAs[64+lane] = a1;
        float* op = out1 + ((size_t)b*(TT-1) + n)*SS;
        op[lane] = a0; op[64+lane] = a1;
    }
    __syncthreads();
    // ctx = sum_s a[s] * enc_out[b,s,:]
    int c4 = tid*4;
    float av0=0, av1=0, av2=0, av3=0;
    const u16* eb = enc_out + (size_t)b*SS*HH + c4;
    for (int s=0; s<SS; s++){
        float as = sAs[s];
        uint2 u = *(const uint2*)(eb + (size_t)s*HH);
        const u16* pu = (const u16*)&u;
        av0 += as * bf2f(pu[0]);
        av1 += as * bf2f(pu[1]);
        av2 += as * bf2f(pu[2]);
        av3 += as * bf2f(pu[3]);
    }
    u16* ch = a0h + (size_t)b*2560 + 512 + c4;
    u16* cl = a0l + (size_t)b*2560 + 512 + c4;
    float av[4] = {av0,av1,av2,av3};
    #pragma unroll
    for (int k=0;k<4;k++){
        u16 hi = f2bf(av[k]); ch[k] = hi; cl[k] = f2bf(av[k] - bf2f(hi));
    }
    // emb = dec_embed[tgt[b, n]]
    int tok = tgt[b*TT + n];
    const float* ep = dec_embed + (size_t)tok*EE;
    u16* ehp = a0h + (size_t)b*2560;
    u16* elp = a0l + (size_t)b*2560;
    #pragma unroll
    for (int k=0;k<2;k++){
        int e = tid*2 + k;
        float x = ep[e];
        u16 hi = f2bf(x);
        ehp[e] = hi; elp[e] = f2bf(x - bf2f(hi));
    }
}

// ---------------- prep / utility kernels ----------------
__global__ void permute_convert_kernel(const float* __restrict__ s, u16* __restrict__ d,
    int hid, int cols, int dld, int doff, int total){
    int i = blockIdx.x*256 + threadIdx.x;
    if (i >= total) return;
    int p = i / cols, c = i - p*cols;
    int j = p >> 2, q = p & 3;
    d[(size_t)p*dld + doff + c] = f2bf(s[((size_t)q*hid + j)*cols + c]);
}
__global__ void permute_convert_split_kernel(const float* __restrict__ s, u16* __restrict__ dh,
    u16* __restrict__ dl, int hid, int cols, int dld, int doff, int total){
    int i = blockIdx.x*256 + threadIdx.x;
    if (i >= total) return;
    int p = i / cols, c = i - p*cols;
    int j = p >> 2, q = p & 3;
    float x = s[((size_t)q*hid + j)*cols + c];
    u16 hi = f2bf(x);
    dh[(size_t)p*dld + doff + c] = hi;
    dl[(size_t)p*dld + doff + c] = f2bf(x - bf2f(hi));
}
__global__ void permute_bias_kernel(const float* __restrict__ s, float* __restrict__ d, int hid){
    int p = blockIdx.x*256 + threadIdx.x;
    if (p >= 4*hid) return;
    int j = p >> 2, q = p & 3;
    d[p] = s[q*hid + j];
}
__global__ void convert_kernel(const float* __restrict__ s, int sld, int soff,
    u16* __restrict__ d, int dld, int cols, int total){
    int i = blockIdx.x*256 + threadIdx.x;
    if (i >= total) return;
    int r = i / cols, c = i - r*cols;
    d[(size_t)r*dld + c] = f2bf(s[(size_t)r*sld + soff + c]);
}
__global__ void convert_split_kernel(const float* __restrict__ s, int sld, int soff,
    u16* __restrict__ dh, u16* __restrict__ dl, int dld, int cols, int total){
    int i = blockIdx.x*256 + threadIdx.x;
    if (i >= total) return;
    int r = i / cols, c = i - r*cols;
    float x = s[(size_t)r*sld + soff + c];
    u16 hi = f2bf(x);
    dh[(size_t)r*dld + c] = hi;
    dl[(size_t)r*dld + c] = f2bf(x - bf2f(hi));
}
// gather embeddings for a CH-timestep chunk starting at t0: rows (t_local*256+b)
__global__ void gather_chunk_kernel(const int* __restrict__ src, const float* __restrict__ emb,
    u16* __restrict__ xe, int t0){
    int i = blockIdx.x*256 + threadIdx.x;       // CH*256*512
    int m = i >> 9, e = i & 511;
    int tl = m >> 8, b = m & 255;
    int tok = src[b*SS + t0 + tl];
    xe[i] = f2bf(emb[(size_t)tok*EE + e]);
}
__global__ void zero_u16_kernel(u16* p, int n){
    int i = blockIdx.x*256 + threadIdx.x; if (i < n) p[i] = 0;
}
__global__ void zero_f32_kernel(float* p, int n){
    int i = blockIdx.x*256 + threadIdx.x; if (i < n) p[i] = 0.f;
}
__global__ void zero_out0_kernel(float* out0){
    int i = blockIdx.x*256 + threadIdx.x;       // 256*256
    int b = i >> 8, v = i & 255;
    out0[(size_t)b*TT*VV + v] = 0.f;
}
__global__ void dec_init_kernel(const u16* h0f, const u16* h0b, const u16* h1f, const u16* h1b,
    const float* c0f, const float* c0b, const float* c1f, const float* c1b,
    u16* a0h, u16* a0l, u16* a1h, u16* a1l, float* c0, float* c1)
{
    int i = blockIdx.x*256 + threadIdx.x;       // 256*1024
    int m = i >> 10, j = i & 1023;
    u16 h0 = (j < 512) ? h0f[m*512 + j] : h0b[m*512 + j - 512];
    u16 h1 = (j < 512) ? h1f[m*512 + j] : h1b[m*512 + j - 512];
    float cc0 = (j < 512) ? c0f[m*512 + j] : c0b[m*512 + j - 512];
    float cc1 = (j < 512) ? c1f[m*512 + j] : c1b[m*512 + j - 512];
    a0h[(size_t)m*2560 + 1536 + j] = h0; a0l[(size_t)m*2560 + 1536 + j] = 0;
    a1h[(size_t)m*2048 + 1024 + j] = h1; a1l[(size_t)m*2048 + 1024 + j] = 0;
    c0[i] = cc0; c1[i] = cc1;
}

// ---------------- host ----------------
extern "C" void kernel_launch(void* const* d_in, const int* in_sizes, int n_in,
                              void* d_out, int out_size, void* d_ws, size_t ws_size,
                              hipStream_t stream)
{
    (void)in_sizes; (void)n_in; (void)out_size;
    // diagnostic guard: if workspace is too small, fail cleanly (absmax = max|ref|)
    const size_t NEED = 230100000;   // ~219.5 MB actual footprint + slack
    if (ws_size < NEED) return;

    const int*   src = (const int*)d_in[0];
    const int*   tgt = (const int*)d_in[1];
    const float* enc_embed = (const float*)d_in[2];
    const float* dec_embed = (const float*)d_in[3];
    const float* ew[4][3] = {
        {(const float*)d_in[4],  (const float*)d_in[5],  (const float*)d_in[6]},
        {(const float*)d_in[7],  (const float*)d_in[8],  (const float*)d_in[9]},
        {(const float*)d_in[10], (const float*)d_in[11], (const float*)d_in[12]},
        {(const float*)d_in[13], (const float*)d_in[14], (const float*)d_in[15]},
    };
    const float* d0_wih = (const float*)d_in[16];
    const float* d0_whh = (const float*)d_in[17];
    const float* d0_b   = (const float*)d_in[18];
    const float* d1_wih = (const float*)d_in[19];
    const float* d1_whh = (const float*)d_in[20];
    const float* d1_b   = (const float*)d_in[21];
    const float* attn_w1 = (const float*)d_in[22];
    const float* attn_b1 = (const float*)d_in[23];
    const float* attn_w2 = (const float*)d_in[24];
    const float* attn_b2 = (const float*)d_in[25];
    const float* fc_w = (const float*)d_in[26];
    const float* fc_b = (const float*)d_in[27];

    float* out0 = (float*)d_out;
    float* out1 = out0 + (size_t)BB*TT*VV;

    char* base = (char*)d_ws;
    size_t off = 0;
    auto alloc = [&](size_t nbytes)->char*{
        char* p = base + off;
        off += (nbytes + 255) & ~(size_t)255;
        return p;
    };
    // ---- small persistent (~20 MB) ----
    float* b_e[4];
    for (int d2=0; d2<4; d2++) b_e[d2] = (float*)alloc(2048*4);
    float* b0p = (float*)alloc(4096*4);
    float* b1p = (float*)alloc(4096*4);
    u16* hbuf    = (u16*)alloc((size_t)8*256*512*2);      // [dir*2+parity]
    float* cbuf  = (float*)alloc((size_t)4*256*512*4);    // [dir]
    u16* bufA0h = (u16*)alloc((size_t)2*256*2560*2);
    u16* bufA0l = (u16*)alloc((size_t)2*256*2560*2);
    u16* bufA1h = (u16*)alloc((size_t)2*256*2048*2);
    u16* bufA1l = (u16*)alloc((size_t)2*256*2048*2);
    float* c0 = (float*)alloc((size_t)256*1024*4);
    float* c1 = (float*)alloc((size_t)256*1024*4);
    float* qp = (float*)alloc((size_t)256*1024*4);
    // ---- big persistent ----
    u16* enc_out = (u16*)alloc((size_t)32768*1024*2);     // alive through decoder
    u16* x1      = (u16*)alloc((size_t)32768*1024*2);     // overlay: x1 -> enc_prj
    u16* enc_prj = x1;
    // ---- time-shared region D: encoder scratch (44 MB) THEN decoder weights (78.6 MB) ----
    char* D = alloc(78643200);
    // encoder-phase carve
    size_t doff = 0;
    auto carve = [&](size_t nbytes)->char*{ char* p = D + doff; doff += nbytes; return p; };
    const int in_dim_e[4] = {512,512,1024,1024};
    u16* wih_e[4]; u16* whh_e[4];
    for (int d2=0; d2<4; d2++){
        wih_e[d2] = (u16*)carve((size_t)2048*in_dim_e[d2]*2);
        whh_e[d2] = (u16*)carve((size_t)2048*512*2);
    }
    u16* w1enc = (u16*)carve((size_t)1024*1024*2);
    u16* xef   = (u16*)carve((size_t)CH*256*512*2);
    u16* xeb   = (u16*)carve((size_t)CH*256*512*2);
    u16* preA  = (u16*)carve((size_t)CH*256*2048*2);
    u16* preB  = (u16*)carve((size_t)CH*256*2048*2);
    // decoder-phase carve (reuses D from offset 0 — written only after encoder done)
    doff = 0;
    u16* W0h = (u16*)carve((size_t)4096*2560*2);
    u16* W0l = (u16*)carve((size_t)4096*2560*2);
    u16* W1h = (u16*)carve((size_t)4096*2048*2);
    u16* W1l = (u16*)carve((size_t)4096*2048*2);
    u16* w1q = (u16*)carve((size_t)1024*1024*2);
    u16* fch = (u16*)carve((size_t)256*1024*2);
    u16* fcl = (u16*)carve((size_t)256*1024*2);

    const size_t HSZ2 = 256*512;   // hbuf slot elems
    const size_t CSZ  = 256*512;   // cbuf slot elems
    const size_t A0SZ = 256*2560, A1SZ = 256*2048;

    // ---- encoder weight prep ----
    for (int d2=0; d2<4; d2++){
        int tot = 2048*in_dim_e[d2];
        permute_convert_kernel<<<(tot+255)/256,256,0,stream>>>(ew[d2][0], wih_e[d2], 512, in_dim_e[d2], in_dim_e[d2], 0, tot);
        tot = 2048*512;
        permute_convert_kernel<<<(tot+255)/256,256,0,stream>>>(ew[d2][1], whh_e[d2], 512, 512, 512, 0, tot);
        permute_bias_kernel<<<8,256,0,stream>>>(ew[d2][2], b_e[d2], 512);
    }
    {
        int tw = 1024*1024;
        convert_kernel<<<(tw+255)/256,256,0,stream>>>(attn_w1, 2048, 0, w1enc, 1024, 1024, tw);
    }
    for (int d2=0; d2<4; d2++)
        zero_u16_kernel<<<512,256,0,stream>>>(hbuf + (size_t)(d2*2)*HSZ2, (int)HSZ2);
    zero_f32_kernel<<<2048,256,0,stream>>>(cbuf, 4*(int)CSZ);
    zero_out0_kernel<<<256,256,0,stream>>>(out0);

    // ---- encoder: chunked pre-GEMMs interleaved with scan ----
    for (int layer = 0; layer < 2; layer++){
        const long ldx  = layer ? 1024 : 512;
        const int  dirf = layer*2, dirb = layer*2 + 1;
        for (int c = 0; c < 128/CH; c++){
            const int tf0 = c*CH, tb0 = 128 - CH*(c+1);
            const u16 *Af, *Ab;
            if (layer == 0){
                gather_chunk_kernel<<<CH*512,256,0,stream>>>(src, enc_embed, xef, tf0);
                gather_chunk_kernel<<<CH*512,256,0,stream>>>(src, enc_embed, xeb, tb0);
                Af = xef; Ab = xeb;
            } else {
                Af = x1 + (size_t)tf0*256*1024;
                Ab = x1 + (size_t)tb0*256*1024;
            }
            {
                GArgs a{}; a.A = Af; a.lda = ldx;
                a.Bw = wih_e[dirf]; a.K = ldx; a.bias = b_e[dirf];
                a.Cb = preA; a.ldc = 2048;
                gemm_kernel<2,2,0,0><<<dim3(16, CH*2),256,0,stream>>>(a);
            }
            {
                GArgs a{}; a.A = Ab; a.lda = ldx;
                a.Bw = wih_e[dirb]; a.K = ldx; a.bias = b_e[dirb];
                a.Cb = preB; a.ldc = 2048;
                gemm_kernel<2,2,0,0><<<dim3(16, CH*2),256,0,stream>>>(a);
            }
            for (int i = 0; i < CH; i++){
                int t = c*CH + i;
                GArgs f{}, bq{};
                f.A = hbuf + (size_t)(dirf*2 + (t&1))*HSZ2; f.lda = 512;
                f.Bw = whh_e[dirf]; f.K = 512;
                f.pre = preA + (size_t)i*256*2048; f.ldpre = 2048;
                f.cst = cbuf + (size_t)dirf*CSZ; f.hid = 512;
                if (layer == 0){ f.h1 = x1 + (size_t)t*256*1024;      f.ldh1 = 1024; }
                else           { f.h1 = enc_out + (size_t)t*1024;     f.ldh1 = (long)SS*1024; }
                f.h2 = hbuf + (size_t)(dirf*2 + ((t+1)&1))*HSZ2; f.ldh2 = 512;
                bq = f;
                bq.A = hbuf + (size_t)(dirb*2 + (t&1))*HSZ2;
                bq.Bw = whh_e[dirb];
                bq.pre = preB + (size_t)(CH-1-i)*256*2048;
                bq.cst = cbuf + (size_t)dirb*CSZ;
                if (layer == 0){ bq.h1 = x1 + (size_t)(127-t)*256*1024 + 512; }
                else           { bq.h1 = enc_out + (size_t)(127-t)*1024 + 512; }
                bq.h2 = hbuf + (size_t)(dirb*2 + ((t+1)&1))*HSZ2;
                lstm_step2_kernel<1,2><<<dim3(16,4,2),128,0,stream>>>(f,bq);
            }
        }
    }
    // ---- enc_proj = enc_out @ w1_enc^T  (overwrites x1 region; x1 dead) ----
    {
        GArgs a{}; a.A = enc_out; a.lda = 1024; a.Bw = w1enc; a.K = 1024;
        a.Cb = enc_prj; a.ldc = 1024;
        gemm_kernel<2,2,0,0><<<dim3(8,256),256,0,stream>>>(a);
    }
    // ---- decoder weight prep (region D reuse — encoder scratch now dead) ----
    {
        int tot = 4096*1536;
        permute_convert_split_kernel<<<(tot+255)/256,256,0,stream>>>(d0_wih, W0h, W0l, 1024, 1536, 2560, 0, tot);
        tot = 4096*1024;
        permute_convert_split_kernel<<<(tot+255)/256,256,0,stream>>>(d0_whh, W0h, W0l, 1024, 1024, 2560, 1536, tot);
        permute_bias_kernel<<<16,256,0,stream>>>(d0_b, b0p, 1024);
        tot = 4096*1024;
        permute_convert_split_kernel<<<(tot+255)/256,256,0,stream>>>(d1_wih, W1h, W1l, 1024, 1024, 2048, 0, tot);
        permute_convert_split_kernel<<<(tot+255)/256,256,0,stream>>>(d1_whh, W1h, W1l, 1024, 1024, 2048, 1024, tot);
        permute_bias_kernel<<<16,256,0,stream>>>(d1_b, b1p, 1024);
        int tw = 1024*1024;
        convert_kernel<<<(tw+255)/256,256,0,stream>>>(attn_w1, 2048, 1024, w1q, 1024, 1024, tw);
        int tf = 256*1024;
        convert_split_kernel<<<(tf+255)/256,256,0,stream>>>(fc_w, 1024, 0, fch, fcl, 1024, 1024, tf);
    }
    // ---- decoder init ----
    dec_init_kernel<<<1024,256,0,stream>>>(
        hbuf + 0*2*HSZ2, hbuf + 1*2*HSZ2, hbuf + 2*2*HSZ2, hbuf + 3*2*HSZ2,
        cbuf + 0*CSZ, cbuf + 1*CSZ, cbuf + 2*CSZ, cbuf + 3*CSZ,
        bufA0h, bufA0l, bufA1h, bufA1l, c0, c1);

    // ---- decoder loop ----
    for (int n = 0; n < 127; n++){
        int pc = n & 1, pn = (n+1) & 1;
        // q_proj = h1 @ w1_q^T + attn_b1
        {
            GArgs a{}; a.A = bufA1h + (size_t)pc*A1SZ + 1024; a.lda = 2048;
            a.Bw = w1q; a.K = 1024; a.bias = attn_b1;
            a.Cf = qp; a.ldc = 1024;
            gemm_kernel<1,2,1,0><<<dim3(8,4),128,0,stream>>>(a);
        }
        attn_kernel<<<256,256,0,stream>>>(enc_prj, enc_out, qp, attn_w2, attn_b2,
            src, tgt, dec_embed, out1,
            bufA0h + (size_t)pc*A0SZ, bufA0l + (size_t)pc*A0SZ, n);
        // dec l0 (split bf16)
        {
            GArgs a{};
            a.A = bufA0h + (size_t)pc*A0SZ; a.A2 = bufA0l + (size_t)pc*A0SZ; a.lda = 2560;
            a.Bw = W0h; a.B2 = W0l; a.K = 2560; a.bias = b0p;
            a.cst = c0; a.hid = 1024;
            a.h1 = bufA0h + (size_t)pn*A0SZ + 1536; a.h1l = bufA0l + (size_t)pn*A0SZ + 1536; a.ldh1 = 2560;
            a.h2 = bufA1h + (size_t)pc*A1SZ;        a.h2l = bufA1l + (size_t)pc*A1SZ;        a.ldh2 = 2048;
            gemm_kernel<1,2,2,1><<<dim3(32,4),128,0,stream>>>(a);
        }
        // dec l1 (split bf16)
        {
            GArgs a{};
            a.A = bufA1h + (size_t)pc*A1SZ; a.A2 = bufA1l + (size_t)pc*A1SZ; a.lda = 2048;
            a.Bw = W1h; a.B2 = W1l; a.K = 2048; a.bias = b1p;
            a.cst = c1; a.hid = 1024;
            a.h1 = bufA1h + (size_t)pn*A1SZ + 1024; a.h1l = bufA1l + (size_t)pn*A1SZ + 1024; a.ldh1 = 2048;
            gemm_kernel<1,2,2,1><<<dim3(32,4),128,0,stream>>>(a);
        }
        // logits = h1 @ fc_w^T + fc_b  -> out0[:, n+1, :]
        {
            GArgs a{};
            a.A = bufA1h + (size_t)pn*A1SZ + 1024; a.A2 = bufA1l + (size_t)pn*A1SZ + 1024; a.lda = 2048;
            a.Bw = fch; a.B2 = fcl; a.K = 1024; a.bias = fc_b;
            a.Cf = out0 + (size_t)(n+1)*VV; a.ldc = (size_t)TT*VV;
            gemm_kernel<1,2,1,1><<<dim3(2,4),128,0,stream>>>(a);
        }
    }
}